// Round 1
// baseline (1265.282 us; speedup 1.0000x reference)
//
#include <hip/hip_runtime.h>
#include <hip/hip_bf16.h>
#include <stdint.h>

#define NB 512
#define NW 40
#define NE 512
#define NH 512
#define NV 12000
#define G4 2048

typedef unsigned short u16;
typedef unsigned int u32;
typedef unsigned long long u64;
typedef __attribute__((ext_vector_type(8))) short short8;
typedef __attribute__((ext_vector_type(4))) float f32x4;

__device__ __forceinline__ unsigned short f2bf(float f) {
  unsigned int u = __float_as_uint(f);
  u += 0x7FFF + ((u >> 16) & 1);
  return (unsigned short)(u >> 16);
}
__device__ __forceinline__ float bf2f(unsigned short b) {
  return __uint_as_float(((unsigned int)b) << 16);
}
__device__ __forceinline__ float loadIn(const void* p, long i, int bf) {
  return bf ? bf2f(((const u16*)p)[i]) : ((const float*)p)[i];
}
// exp-based tanh: |err| ~1e-7 abs, saturates cleanly (exp->inf => 1).
__device__ __forceinline__ float fast_tanh(float x) {
  float ax = __builtin_fabsf(x);
  float t = 1.f - 2.f * __builtin_amdgcn_rcpf(__expf(ax + ax) + 1.f);
  return __builtin_copysignf(t, x);
}
__device__ __forceinline__ float sigm(float x) {
  return __builtin_amdgcn_rcpf(1.f + __expf(-x));
}

// ---------------- dtype detector ----------------
__global__ void detect_kernel(const u16* p, int* flag) {
  __shared__ int cnt;
  int i = threadIdx.x;
  if (i == 0) cnt = 0;
  __syncthreads();
  unsigned short u = p[2 * (i * 1001)];
  int e = (u >> 7) & 0xFF;
  if (e >= 100 && e <= 126) atomicAdd(&cnt, 1);
  __syncthreads();
  if (i == 0) *flag = (cnt >= 32) ? 1 : 0;
}

// ---------------- tableT = bf16(tanh(lookup_W^T)), (V, E) ----------------
__global__ void table_kernel(const void* lookup, const int* flag, u16* tableT) {
  __shared__ float tile[64][65];
  int bf = *flag;
  int v0 = blockIdx.x * 64, e0 = blockIdx.y * 64;
  int tx = threadIdx.x, ty = threadIdx.y;  // (64,4)
#pragma unroll
  for (int r = 0; r < 16; ++r) {
    int e = r * 4 + ty, v = tx;
    if (v0 + v < NV)
      tile[e][v] = tanhf(loadIn(lookup, (long)(e0 + e) * NV + v0 + v, bf));
  }
  __syncthreads();
#pragma unroll
  for (int r = 0; r < 16; ++r) {
    int v = r * 4 + ty, e = tx;
    if (v0 + v < NV)
      tableT[(long)(v0 + v) * NE + e0 + e] = f2bf(tile[e][v]);
  }
}

// ---------------- emb (W*B, E) bf16, rows tb = t*NB+b ----------------
__global__ void embed_kernel(const int* __restrict__ qv,
                             const u16* __restrict__ tableT,
                             u16* __restrict__ emb) {
  int tid = blockIdx.x * 256 + threadIdx.x;
  int token = tid >> 6;
  int chunk = tid & 63;
  int tt = token / NB, b = token % NB;
  int q = qv[b * NW + tt];
  uint4 val = make_uint4(0u, 0u, 0u, 0u);
  if (q > 0) val = *(const uint4*)(tableT + (long)(q - 1) * NE + chunk * 8);
  *(uint4*)(emb + (long)token * NE + chunk * 8) = val;
}

// ---------------- pack weights: Wc[d] rows = [wih | whh], bf16 ------------
__global__ void pack_kernel(const void* wih0, const void* whh0, const void* b0,
                            const void* wih1, const void* whh1, const void* b1,
                            const int* flag, u16* Wc0, u16* Wc1, float* bsum) {
  const long N0 = 2L * G4 * 1024, N1 = 2L * G4 * 1536;
  long idx = (long)blockIdx.x * 256 + threadIdx.x;
  int bf = *flag;
  if (idx < N0) {
    int d = (int)(idx / (G4 * 1024));
    int rem = (int)(idx % (long)(G4 * 1024));
    int g = rem / 1024, k = rem % 1024;
    float v = (k < 512) ? loadIn(wih0, ((long)d * G4 + g) * 512 + k, bf)
                        : loadIn(whh0, ((long)d * G4 + g) * 512 + (k - 512), bf);
    Wc0[idx] = f2bf(v);
  } else if (idx < N0 + N1) {
    long i2 = idx - N0;
    int d = (int)(i2 / (G4 * 1536));
    int rem = (int)(i2 % (long)(G4 * 1536));
    int g = rem / 1536, k = rem % 1536;
    float v = (k < 1024) ? loadIn(wih1, ((long)d * G4 + g) * 1024 + k, bf)
                         : loadIn(whh1, ((long)d * G4 + g) * 512 + (k - 1024), bf);
    Wc1[i2] = f2bf(v);
  } else if (idx < N0 + N1 + 2L * 2 * G4) {
    long i3 = idx - N0 - N1;  // [layer][d][g]
    int layer = (int)(i3 / (2 * G4));
    int d = (int)((i3 / G4) & 1);
    int g = (int)(i3 % G4);
    const void* bb = layer ? b1 : b0;
    float v = loadIn(bb, (long)d * 2 * G4 + g, bf) +
              loadIn(bb, (long)d * 2 * G4 + G4 + g, bf);
    bsum[i3] = v;
  }
}

// ---------------- zero the barrier (8 KB) ----------------
__global__ void zero_bar(unsigned int* bar) {
  bar[blockIdx.x * 256 + threadIdx.x] = 0u;
}

// ---------------- xg GEMM: xg[t][d][col][b][jn*4+g] = X@Wih^T + bias ------
// 128x128 tile, BK=64, m97-style staging, 4 waves 2x2.
// R8: 1D grid + supertile swizzle (4 bx x 8 by contiguous) so A-tiles
// (4x256KB) and B-tiles (8x256KB) stay cache-resident across reuse.
__global__ __launch_bounds__(256, 2) void xg_gemm(
    const u16* __restrict__ X, int Kx, int Kfull, const u16* __restrict__ Wc,
    const float* __restrict__ bsumL, u16* __restrict__ xg) {
  __shared__ __align__(16) char lds[32768];  // A 16K + B 16K
  const int tid = threadIdx.x;
  const int lane = tid & 63, wv = tid >> 6;
  const int wm = wv & 1, wn = wv >> 1;
  const int col = lane & 15, quad = lane >> 4;
  const int s = blockIdx.x >> 5, w = blockIdx.x & 31;
  const int bx = (s % 40) * 4 + (w & 3);
  const int by = (s / 40) * 8 + (w >> 2);
  const int tb0 = bx * 128;
  const int d = by >> 4, colb = by & 15, j0 = colb * 32;

  f32x4 zero = {0.f, 0.f, 0.f, 0.f};
  f32x4 acc[4][4];
#pragma unroll
  for (int i = 0; i < 4; ++i)
#pragma unroll
    for (int j = 0; j < 4; ++j) acc[i][j] = zero;

  const int iters = Kx >> 6;
  for (int it = 0; it < iters; ++it) {
    int k0 = it << 6;
#pragma unroll
    for (int p = 0; p < 8; ++p) {
      int c = p * 256 + tid;  // [0,2048)
      const u16* gsrc;
      if (c < 1024) {  // A rows 0..127
        int r = c >> 3, sl = c & 7;
        int kk = k0 + ((sl * 8) ^ ((r & 7) << 3));
        gsrc = X + (long)(tb0 + r) * Kx + kk;
      } else {
        int cb = c - 1024;
        int r = cb >> 3, sl = cb & 7;
        int kk = k0 + ((sl * 8) ^ ((r & 7) << 3));
        int grow = (r >> 5) * 512 + j0 + (r & 31);
        gsrc = Wc + ((long)d * G4 + grow) * Kfull + kk;
      }
      __builtin_amdgcn_global_load_lds(
          (const __attribute__((address_space(1))) void*)(const void*)gsrc,
          (__attribute__((address_space(3))) void*)(lds + p * 4096 + wv * 1024),
          16, 0, 0);
    }
    __syncthreads();
    const u16* As = (const u16*)lds;
    const u16* Bs = (const u16*)(lds + 16384);
#pragma unroll
    for (int ks = 0; ks < 2; ++ks) {
      short8 afr[4], bfr[4];
#pragma unroll
      for (int mf = 0; mf < 4; ++mf) {
        int rm = wm * 64 + mf * 16 + col;
        int sl = (ks * 32 + quad * 8) ^ ((rm & 7) << 3);
        afr[mf] = *(const short8*)(As + rm * 64 + sl);
      }
#pragma unroll
      for (int nf = 0; nf < 4; ++nf) {
        int br = wn * 64 + nf * 16 + col;
        int sl = (ks * 32 + quad * 8) ^ ((br & 7) << 3);
        bfr[nf] = *(const short8*)(Bs + br * 64 + sl);
      }
#pragma unroll
      for (int mf = 0; mf < 4; ++mf)
#pragma unroll
        for (int nf = 0; nf < 4; ++nf)
          acc[mf][nf] = __builtin_amdgcn_mfma_f32_16x16x32_bf16(
              afr[mf], bfr[nf], acc[mf][nf], 0, 0, 0);
    }
    __syncthreads();
  }

  float bias[4];
#pragma unroll
  for (int nf = 0; nf < 4; ++nf) {
    int n = wn * 64 + nf * 16 + col;
    bias[nf] = bsumL[d * G4 + (n >> 5) * 512 + j0 + (n & 31)];
  }
#pragma unroll
  for (int mf = 0; mf < 4; ++mf)
#pragma unroll
    for (int nf = 0; nf < 4; ++nf) {
      int n = wn * 64 + nf * 16 + col;
      int g = n >> 5, jn = n & 31;
#pragma unroll
      for (int r = 0; r < 4; ++r) {
        int m = wm * 64 + mf * 16 + quad * 4 + r;
        int tb = tb0 + m, t = tb >> 9, b = tb & 511;
        long oi = ((((long)t * 2 + d) * 16 + colb) * 512 + b) * 128 + jn * 4 + g;
        xg[oi] = f2bf(acc[mf][nf][r] + bias[nf]);
      }
    }
}

// ---------------- persistent bidirectional LSTM recurrence ----------------
// R9: latency-hiding restructure.
//  * Each block owns BOTH directions of a (64-row, 16-col) slice:
//    colb = bid&31 (16 h-cols), mi = bid>>5 (64 batch rows). Whh for both
//    directions (128 rows x 512) is LDS-resident (128 KB, same as before).
//  * Per step, the d=0 and d=1 phases interleave: while this block runs d1,
//    peers' d0(t) flag stores propagate, so the d0 wait at step t+1 is
//    (nearly) free. The old design exposed the full LLC flag round-trip
//    (~1-2us) serially every step. All 256 CUs stay busy.
//  * h(t-1) loads go straight into MFMA A-fragments via agent-scope (sc1)
//    8B relaxed-atomic loads (each wave's A-rows wv*16+col are private to
//    it) -- no LDS staging, no per-K-chunk barriers: 3 syncthreads/phase
//    instead of 7, one pipelined LLC latency instead of 4 exposed drains.
//  * Barrier -> per-writer flag slots: writer colb stores bar[gid*32+colb]
//    = t+1 after its h stores drain; readers (wave0 lanes) poll the 32-slot
//    line (128 B) until all >= t. No fetch_add RMW serialization.
//  * tanhf -> exp-based fast_tanh (cell VALU is on the serial path).
// 2-slot hbuf stays safe: a block stores h_d(t+1) only after all 32 writers
// signaled t (spin), which transitively implies every block finished its
// reads of h_d(t-1) (reads precede stores in program order).
__global__ __launch_bounds__(256, 1) void lstm_pers(
    const u16* __restrict__ xg, const u16* __restrict__ Wc, int Kfull, int Kx,
    u16* __restrict__ hbuf, u16* __restrict__ h0cat, void* __restrict__ outp,
    const int* __restrict__ qlen, const int* __restrict__ flag,
    unsigned int* bar, int layer) {
  __shared__ __align__(16) char lds[133120];  // Whh 128K + h-pack 2K
  const int tid = threadIdx.x;
  const int lane = tid & 63, wv = tid >> 6;
  const int col = lane & 15, quad = lane >> 4;
  const int l = blockIdx.x;
  const int colb = l & 31;  // 32 column slices of 16
  const int mi = l >> 5;    // 8 batch groups of 64
  const int j0 = colb * 16;
  const int m0 = mi * 64;

  // ---- preload Whh for BOTH directions: LDS rows r=[d][g][j-j0], [128][512]
#pragma unroll
  for (int p = 0; p < 32; ++p) {
    int c = p * 256 + tid;
    int row = c >> 6, rem = c & 63;
    int kc = rem >> 3, sl = rem & 7;
    int dr = row >> 6;
    int grow = ((row >> 4) & 3) * 512 + j0 + (row & 15);
    int gk = Kx + kc * 64 + ((sl * 8) ^ ((row & 7) << 3));
    const u16* gsrc = Wc + ((long)dr * G4 + grow) * Kfull + gk;
    __builtin_amdgcn_global_load_lds(
        (const __attribute__((address_space(1))) void*)(const void*)gsrc,
        (__attribute__((address_space(3))) void*)(lds + p * 4096 + wv * 1024),
        16, 0, 0);
  }
  const u16* Bs = (const u16*)lds;
  u16* hLDS = (u16*)(lds + 131072);  // epilogue pack [64 m][16 j]

  float creg[2][4];
#pragma unroll
  for (int i = 0; i < 2; ++i)
#pragma unroll
    for (int r = 0; r < 4; ++r) creg[i][r] = 0.f;
  const int isbf = *flag;
  f32x4 zero = {0.f, 0.f, 0.f, 0.f};

  __syncthreads();  // Whh resident

#pragma unroll 1
  for (int t = 0; t < NW; ++t) {
#pragma unroll
    for (int d = 0; d < 2; ++d) {
      const int tq = d ? (NW - 1 - t) : t;
      const int gid = mi * 2 + d;

      // xg prefetch: cell (m = wv*16+quad*4+r, j = col)
      ushort4 xgv[4];
      const u16* xgt =
          xg + ((((long)tq * 2 + d) * 16 + (colb >> 1)) * 512 + m0) * 128;
#pragma unroll
      for (int r = 0; r < 4; ++r) {
        int m = wv * 16 + quad * 4 + r;
        xgv[r] = *(const ushort4*)(xgt + m * 128 + ((colb & 1) * 16 + col) * 4);
      }

      f32x4 acc[4];
#pragma unroll
      for (int g = 0; g < 4; ++g) acc[g] = zero;

      if (t > 0) {
        // ---- wait for the 32 writers of (mi,d) to have stored h(t-1) ----
        if (wv == 0) {
          u32* sp = bar + gid * 32 + (lane & 31);
          while (__ballot((int)(__hip_atomic_load(sp, __ATOMIC_RELAXED,
                                                  __HIP_MEMORY_SCOPE_AGENT) <
                                (u32)t)))
            __builtin_amdgcn_s_sleep(1);
        }
        __syncthreads();

        // ---- A-fragments direct from LLC: rows wv*16+col are wave-private
        const u16* hp = hbuf + ((t - 1) & 1) * (2L * NB * NH) +
                        ((long)d * NB + m0 + wv * 16 + col) * NH;
        short8 afr[16];
#pragma unroll
        for (int it = 0; it < 4; ++it)
#pragma unroll
          for (int ks = 0; ks < 4; ++ks) {
            const u64* p = (const u64*)(hp + it * 128 + ks * 32 + quad * 8);
            union {
              short8 v;
              u64 q[2];
            } u;
            u.q[0] = __hip_atomic_load((u64*)p, __ATOMIC_RELAXED,
                                       __HIP_MEMORY_SCOPE_AGENT);
            u.q[1] = __hip_atomic_load((u64*)p + 1, __ATOMIC_RELAXED,
                                       __HIP_MEMORY_SCOPE_AGENT);
            afr[it * 4 + ks] = u.v;
          }
#pragma unroll
        for (int it = 0; it < 4; ++it)
#pragma unroll
          for (int ks = 0; ks < 4; ++ks) {
            const int kc = it * 128 + ks * 32 + quad * 8;
#pragma unroll
            for (int g = 0; g < 4; ++g) {
              int br = d * 64 + g * 16 + col;
              int slb = (kc & 63) ^ ((br & 7) << 3);
              short8 bfr = *(const short8*)(Bs + br * 512 + (kc & ~63) + slb);
              acc[g] = __builtin_amdgcn_mfma_f32_16x16x32_bf16(
                  afr[it * 4 + ks], bfr, acc[g], 0, 0, 0);
            }
          }
      }

      // ---- register-only cell update; pack h into 2 KB LDS ----
#pragma unroll
      for (int r = 0; r < 4; ++r) {
        int m = wv * 16 + quad * 4 + r;
        float gi = acc[0][r] + bf2f(xgv[r].x);
        float gf = acc[1][r] + bf2f(xgv[r].y);
        float gg = acc[2][r] + bf2f(xgv[r].z);
        float go = acc[3][r] + bf2f(xgv[r].w);
        float si = sigm(gi);
        float sf = sigm(gf);
        float so = sigm(go);
        float cn = sf * creg[d][r] + si * fast_tanh(gg);
        float h = so * fast_tanh(cn);
        creg[d][r] = cn;
        hLDS[m * 16 + col] = f2bf(h);
        // fp32 output path: store full-precision h directly (rare rows)
        if (layer == 1 && !isbf) {
          int bg = m0 + m;
          if (qlen[bg] - 1 == tq)
            ((float*)outp)[(long)bg * (2 * NH) + d * NH + j0 + col] = h;
        }
      }
      __syncthreads();

      // ---- paired coalesced stores from the pack ----
      u16* hnxt = hbuf + (t & 1) * (2L * NB * NH);
#pragma unroll
      for (int p = 0; p < 2; ++p) {
        int c = p * 256 + tid;  // [0,512) pairs
        int m = c >> 3, pr = c & 7;
        u32 hw = ((const u32*)hLDS)[m * 8 + pr];
        int bg = m0 + m, jg = j0 + pr * 2;
        __hip_atomic_store((u32*)(hnxt + ((long)d * NB + bg) * NH + jg), hw,
                           __ATOMIC_RELAXED, __HIP_MEMORY_SCOPE_AGENT);
        if (layer == 0) {
          *(u32*)(h0cat + ((long)tq * NB + bg) * (2 * NH) + d * NH + jg) = hw;
        } else if (isbf && qlen[bg] - 1 == tq) {
          *(u32*)((u16*)outp + (long)bg * (2 * NH) + d * NH + jg) = hw;
        }
      }

      // ---- signal: per-writer slot, after stores drain ----
      if (t < NW - 1) {
        __syncthreads();  // drains vmcnt: h stores visible at LLC
        if (tid == 0)
          __hip_atomic_store(bar + gid * 32 + colb, (u32)(t + 1),
                             __ATOMIC_RELAXED, __HIP_MEMORY_SCOPE_AGENT);
      }
    }
  }
}

extern "C" void kernel_launch(void* const* d_in, const int* in_sizes, int n_in,
                              void* d_out, int out_size, void* d_ws,
                              size_t ws_size, hipStream_t stream) {
  const int* qv = (const int*)d_in[0];
  const int* ql = (const int*)d_in[1];
  const void* lookup = d_in[2];
  const void* wih0 = d_in[3];
  const void* whh0 = d_in[4];
  const void* b0 = d_in[5];
  const void* wih1 = d_in[6];
  const void* whh1 = d_in[7];
  const void* b1 = d_in[8];

  char* ws = (char*)d_ws;
  size_t off = 0;
  int* flag = (int*)ws;                 off += 256;
  unsigned int* bar = (unsigned int*)(ws + off); off += 8192;
  float* bsum = (float*)(ws + off);     off += 2L * 2 * G4 * 4;        // 32 KB
  u16* Wc0 = (u16*)(ws + off);          off += 2L * G4 * 1024 * 2;     // 8 MB
  u16* Wc1 = (u16*)(ws + off);          off += 2L * G4 * 1536 * 2;     // 12 MB
  u16* hbuf = (u16*)(ws + off);         off += 2L * 2 * NB * NH * 2;   // 2 MB
  u16* h0cat = (u16*)(ws + off);        off += (size_t)NW * NB * 2 * NH * 2; // 40 MB
  u16* emb = (u16*)(ws + off);          off += (size_t)NW * NB * NE * 2;     // 20 MB
  u16* xg = (u16*)(ws + off);           off += (size_t)NW * 2 * 16 * 512 * 128 * 2; // 168 MB
  u16* tableT = h0cat;  // tableT (12.3 MB) aliases h0cat: dead before layer0

  detect_kernel<<<1, 64, 0, stream>>>((const u16*)lookup, flag);
  table_kernel<<<dim3(188, 8), dim3(64, 4), 0, stream>>>(lookup, flag, tableT);
  {
    long total = 2L * G4 * 1024 + 2L * G4 * 1536 + 2L * 2 * G4;
    int blocks = (int)((total + 255) / 256);
    pack_kernel<<<blocks, 256, 0, stream>>>(wih0, whh0, b0, wih1, whh1, b1,
                                            flag, Wc0, Wc1, bsum);
  }
  embed_kernel<<<NW * NB / 4, 256, 0, stream>>>(qv, tableT, emb);

  // layer 0
  xg_gemm<<<5120, 256, 0, stream>>>(emb, 512, 1024, Wc0, bsum, xg);
  zero_bar<<<8, 256, 0, stream>>>(bar);
  lstm_pers<<<256, 256, 0, stream>>>(xg, Wc0, 1024, 512, hbuf, h0cat, d_out,
                                     ql, flag, bar, 0);
  // layer 1
  xg_gemm<<<5120, 256, 0, stream>>>(h0cat, 1024, 1536, Wc1, bsum + 2 * G4, xg);
  zero_bar<<<8, 256, 0, stream>>>(bar);
  lstm_pers<<<256, 256, 0, stream>>>(xg, Wc1, 1536, 1024, hbuf, h0cat, d_out,
                                     ql, flag, bar, 1);
}

// Round 2
// 1056.079 us; speedup vs baseline: 1.1981x; 1.1981x over previous
//
#include <hip/hip_runtime.h>
#include <hip/hip_bf16.h>
#include <stdint.h>

#define NB 512
#define NW 40
#define NE 512
#define NH 512
#define NV 12000
#define G4 2048

typedef unsigned short u16;
typedef unsigned int u32;
typedef unsigned long long u64;
typedef __attribute__((ext_vector_type(8))) short short8;
typedef __attribute__((ext_vector_type(4))) float f32x4;

__device__ __forceinline__ unsigned short f2bf(float f) {
  unsigned int u = __float_as_uint(f);
  u += 0x7FFF + ((u >> 16) & 1);
  return (unsigned short)(u >> 16);
}
__device__ __forceinline__ float bf2f(unsigned short b) {
  return __uint_as_float(((unsigned int)b) << 16);
}
__device__ __forceinline__ float loadIn(const void* p, long i, int bf) {
  return bf ? bf2f(((const u16*)p)[i]) : ((const float*)p)[i];
}
// exp-based tanh: |err| ~1e-7 abs, saturates cleanly (exp->inf => 1).
__device__ __forceinline__ float fast_tanh(float x) {
  float ax = __builtin_fabsf(x);
  float t = 1.f - 2.f * __builtin_amdgcn_rcpf(__expf(ax + ax) + 1.f);
  return __builtin_copysignf(t, x);
}
__device__ __forceinline__ float sigm(float x) {
  return __builtin_amdgcn_rcpf(1.f + __expf(-x));
}

// ---------------- dtype detector ----------------
__global__ void detect_kernel(const u16* p, int* flag) {
  __shared__ int cnt;
  int i = threadIdx.x;
  if (i == 0) cnt = 0;
  __syncthreads();
  unsigned short u = p[2 * (i * 1001)];
  int e = (u >> 7) & 0xFF;
  if (e >= 100 && e <= 126) atomicAdd(&cnt, 1);
  __syncthreads();
  if (i == 0) *flag = (cnt >= 32) ? 1 : 0;
}

// ---------------- tableT = bf16(tanh(lookup_W^T)), (V, E) ----------------
__global__ void table_kernel(const void* lookup, const int* flag, u16* tableT) {
  __shared__ float tile[64][65];
  int bf = *flag;
  int v0 = blockIdx.x * 64, e0 = blockIdx.y * 64;
  int tx = threadIdx.x, ty = threadIdx.y;  // (64,4)
#pragma unroll
  for (int r = 0; r < 16; ++r) {
    int e = r * 4 + ty, v = tx;
    if (v0 + v < NV)
      tile[e][v] = tanhf(loadIn(lookup, (long)(e0 + e) * NV + v0 + v, bf));
  }
  __syncthreads();
#pragma unroll
  for (int r = 0; r < 16; ++r) {
    int v = r * 4 + ty, e = tx;
    if (v0 + v < NV)
      tableT[(long)(v0 + v) * NE + e0 + e] = f2bf(tile[e][v]);
  }
}

// ---------------- emb (W*B, E) bf16, rows tb = t*NB+b ----------------
__global__ void embed_kernel(const int* __restrict__ qv,
                             const u16* __restrict__ tableT,
                             u16* __restrict__ emb) {
  int tid = blockIdx.x * 256 + threadIdx.x;
  int token = tid >> 6;
  int chunk = tid & 63;
  int tt = token / NB, b = token % NB;
  int q = qv[b * NW + tt];
  uint4 val = make_uint4(0u, 0u, 0u, 0u);
  if (q > 0) val = *(const uint4*)(tableT + (long)(q - 1) * NE + chunk * 8);
  *(uint4*)(emb + (long)token * NE + chunk * 8) = val;
}

// ---------------- pack weights: Wc[d] rows = [wih | whh], bf16 ------------
__global__ void pack_kernel(const void* wih0, const void* whh0, const void* b0,
                            const void* wih1, const void* whh1, const void* b1,
                            const int* flag, u16* Wc0, u16* Wc1, float* bsum) {
  const long N0 = 2L * G4 * 1024, N1 = 2L * G4 * 1536;
  long idx = (long)blockIdx.x * 256 + threadIdx.x;
  int bf = *flag;
  if (idx < N0) {
    int d = (int)(idx / (G4 * 1024));
    int rem = (int)(idx % (long)(G4 * 1024));
    int g = rem / 1024, k = rem % 1024;
    float v = (k < 512) ? loadIn(wih0, ((long)d * G4 + g) * 512 + k, bf)
                        : loadIn(whh0, ((long)d * G4 + g) * 512 + (k - 512), bf);
    Wc0[idx] = f2bf(v);
  } else if (idx < N0 + N1) {
    long i2 = idx - N0;
    int d = (int)(i2 / (G4 * 1536));
    int rem = (int)(i2 % (long)(G4 * 1536));
    int g = rem / 1536, k = rem % 1536;
    float v = (k < 1024) ? loadIn(wih1, ((long)d * G4 + g) * 1024 + k, bf)
                         : loadIn(whh1, ((long)d * G4 + g) * 512 + (k - 1024), bf);
    Wc1[i2] = f2bf(v);
  } else if (idx < N0 + N1 + 2L * 2 * G4) {
    long i3 = idx - N0 - N1;  // [layer][d][g]
    int layer = (int)(i3 / (2 * G4));
    int d = (int)((i3 / G4) & 1);
    int g = (int)(i3 % G4);
    const void* bb = layer ? b1 : b0;
    float v = loadIn(bb, (long)d * 2 * G4 + g, bf) +
              loadIn(bb, (long)d * 2 * G4 + G4 + g, bf);
    bsum[i3] = v;
  }
}

// ---------------- zero the barrier (8 KB) ----------------
__global__ void zero_bar(unsigned int* bar) {
  bar[blockIdx.x * 256 + threadIdx.x] = 0u;
}

// ---------------- xg GEMM: xg[t][d][col][b][jn*4+g] = X@Wih^T + bias ------
// 128x128 tile, BK=64, m97-style staging, 4 waves 2x2.
// 1D grid + supertile swizzle (4 bx x 8 by contiguous) so A-tiles
// (4x256KB) and B-tiles (8x256KB) stay cache-resident across reuse.
__global__ __launch_bounds__(256, 2) void xg_gemm(
    const u16* __restrict__ X, int Kx, int Kfull, const u16* __restrict__ Wc,
    const float* __restrict__ bsumL, u16* __restrict__ xg) {
  __shared__ __align__(16) char lds[32768];  // A 16K + B 16K
  const int tid = threadIdx.x;
  const int lane = tid & 63, wv = tid >> 6;
  const int wm = wv & 1, wn = wv >> 1;
  const int col = lane & 15, quad = lane >> 4;
  const int s = blockIdx.x >> 5, w = blockIdx.x & 31;
  const int bx = (s % 40) * 4 + (w & 3);
  const int by = (s / 40) * 8 + (w >> 2);
  const int tb0 = bx * 128;
  const int d = by >> 4, colb = by & 15, j0 = colb * 32;

  f32x4 zero = {0.f, 0.f, 0.f, 0.f};
  f32x4 acc[4][4];
#pragma unroll
  for (int i = 0; i < 4; ++i)
#pragma unroll
    for (int j = 0; j < 4; ++j) acc[i][j] = zero;

  const int iters = Kx >> 6;
  for (int it = 0; it < iters; ++it) {
    int k0 = it << 6;
#pragma unroll
    for (int p = 0; p < 8; ++p) {
      int c = p * 256 + tid;  // [0,2048)
      const u16* gsrc;
      if (c < 1024) {  // A rows 0..127
        int r = c >> 3, sl = c & 7;
        int kk = k0 + ((sl * 8) ^ ((r & 7) << 3));
        gsrc = X + (long)(tb0 + r) * Kx + kk;
      } else {
        int cb = c - 1024;
        int r = cb >> 3, sl = cb & 7;
        int kk = k0 + ((sl * 8) ^ ((r & 7) << 3));
        int grow = (r >> 5) * 512 + j0 + (r & 31);
        gsrc = Wc + ((long)d * G4 + grow) * Kfull + kk;
      }
      __builtin_amdgcn_global_load_lds(
          (const __attribute__((address_space(1))) void*)(const void*)gsrc,
          (__attribute__((address_space(3))) void*)(lds + p * 4096 + wv * 1024),
          16, 0, 0);
    }
    __syncthreads();
    const u16* As = (const u16*)lds;
    const u16* Bs = (const u16*)(lds + 16384);
#pragma unroll
    for (int ks = 0; ks < 2; ++ks) {
      short8 afr[4], bfr[4];
#pragma unroll
      for (int mf = 0; mf < 4; ++mf) {
        int rm = wm * 64 + mf * 16 + col;
        int sl = (ks * 32 + quad * 8) ^ ((rm & 7) << 3);
        afr[mf] = *(const short8*)(As + rm * 64 + sl);
      }
#pragma unroll
      for (int nf = 0; nf < 4; ++nf) {
        int br = wn * 64 + nf * 16 + col;
        int sl = (ks * 32 + quad * 8) ^ ((br & 7) << 3);
        bfr[nf] = *(const short8*)(Bs + br * 64 + sl);
      }
#pragma unroll
      for (int mf = 0; mf < 4; ++mf)
#pragma unroll
        for (int nf = 0; nf < 4; ++nf)
          acc[mf][nf] = __builtin_amdgcn_mfma_f32_16x16x32_bf16(
              afr[mf], bfr[nf], acc[mf][nf], 0, 0, 0);
    }
    __syncthreads();
  }

  float bias[4];
#pragma unroll
  for (int nf = 0; nf < 4; ++nf) {
    int n = wn * 64 + nf * 16 + col;
    bias[nf] = bsumL[d * G4 + (n >> 5) * 512 + j0 + (n & 31)];
  }
#pragma unroll
  for (int mf = 0; mf < 4; ++mf)
#pragma unroll
    for (int nf = 0; nf < 4; ++nf) {
      int n = wn * 64 + nf * 16 + col;
      int g = n >> 5, jn = n & 31;
#pragma unroll
      for (int r = 0; r < 4; ++r) {
        int m = wm * 64 + mf * 16 + quad * 4 + r;
        int tb = tb0 + m, t = tb >> 9, b = tb & 511;
        long oi = ((((long)t * 2 + d) * 16 + colb) * 512 + b) * 128 + jn * 4 + g;
        xg[oi] = f2bf(acc[mf][nf][r] + bias[nf]);
      }
    }
}

// ---------------- persistent bidirectional LSTM recurrence ----------------
// R10 = R9's direction-interleave + R8's staged A-datapath.
// R9 post-mortem: MFMA cycles identical R8 vs R9 (33.7 vs 34.4us) -- the
// +120us was pure stall from replacing the pipelined 16B-coalesced
// global_load_lds A-staging with 32x 8B agent-scope scalar loads (scattered
// 32B sectors, all-MALL, issued serially after the wait, zero overlap).
// R10 restores R8's stage(): 4x16KB chunks, stage(it+1) overlapping
// compute(it). Kept from R9 (mechanism unrefuted, now isolated):
//  * block owns BOTH directions of a (64-row, 16-col) slice; Whh for both
//    d (128 rows x 512) LDS-resident. While this block runs d1(t), peers'
//    d0(t) signals propagate -> the d0(t+1) wait hits on first poll.
//  * per-writer flag slots (no fetch_add RMW), 32-lane ballot poll.
// New micro-fix: hbuf (LLC) stores drain before the signal; h0cat/output
// (HBM) stores are issued AFTER the signal so their ~1us HBM ack is off
// the critical sync path (values carried in registers, retired under the
// next phase's barriers).
// LDS: Whh 128K + 2x16K stage = exactly 160 KiB. hLDS pack aliases stage
// buf0 (safe: buf0 last read before the it=2 barrier; pack written after).
__global__ __launch_bounds__(256, 1) void lstm_pers(
    const u16* __restrict__ xg, const u16* __restrict__ Wc, int Kfull, int Kx,
    u16* __restrict__ hbuf, u16* __restrict__ h0cat, void* __restrict__ outp,
    const int* __restrict__ qlen, const int* __restrict__ flag,
    unsigned int* bar, int layer) {
  __shared__ __align__(16) char lds[163840];  // [Whh 128K][stage 2x16K]
  const int tid = threadIdx.x;
  const int lane = tid & 63, wv = tid >> 6;
  const int col = lane & 15, quad = lane >> 4;
  const int l = blockIdx.x;
  const int colb = l & 31;  // 32 column slices of 16
  const int mi = l >> 5;    // 8 batch groups of 64
  const int j0 = colb * 16;
  const int m0 = mi * 64;

  // ---- preload Whh for BOTH directions: LDS rows r=[dr][g][j-j0], [128][512]
#pragma unroll
  for (int p = 0; p < 32; ++p) {
    int c = p * 256 + tid;
    int row = c >> 6, rem = c & 63;
    int kc = rem >> 3, sl = rem & 7;
    int dr = row >> 6;
    int grow = ((row >> 4) & 3) * 512 + j0 + (row & 15);
    int gk = Kx + kc * 64 + ((sl * 8) ^ ((row & 7) << 3));
    const u16* gsrc = Wc + ((long)dr * G4 + grow) * Kfull + gk;
    __builtin_amdgcn_global_load_lds(
        (const __attribute__((address_space(1))) void*)(const void*)gsrc,
        (__attribute__((address_space(3))) void*)(lds + p * 4096 + wv * 1024),
        16, 0, 0);
  }
  const u16* Bs = (const u16*)lds;
  char* hstg = lds + 131072;  // 2 x 16 KB stage bufs; first 2 KB = h-pack
  u16* hLDS = (u16*)hstg;     // epilogue pack [64 m][16 j]

  float creg[2][4];
#pragma unroll
  for (int i = 0; i < 2; ++i)
#pragma unroll
    for (int r = 0; r < 4; ++r) creg[i][r] = 0.f;
  const int isbf = *flag;
  f32x4 zero = {0.f, 0.f, 0.f, 0.f};

  __syncthreads();  // Whh resident

#pragma unroll 1
  for (int t = 0; t < NW; ++t) {
#pragma unroll 1
    for (int d = 0; d < 2; ++d) {
      const int tq = d ? (NW - 1 - t) : t;
      const int gid = mi * 2 + d;

      // xg prefetch (independent of the wait): cell m = wv*16+quad*4+r
      ushort4 xgv[4];
      const u16* xgt =
          xg + ((((long)tq * 2 + d) * 16 + (colb >> 1)) * 512 + m0) * 128;
#pragma unroll
      for (int r = 0; r < 4; ++r) {
        int m = wv * 16 + quad * 4 + r;
        xgv[r] = *(const ushort4*)(xgt + m * 128 + ((colb & 1) * 16 + col) * 4);
      }

      f32x4 acc[4];
#pragma unroll
      for (int g = 0; g < 4; ++g) acc[g] = zero;

      if (t > 0) {
        // ---- wait for the 32 writers of (mi,d) to have stored h(t-1) ----
        if (wv == 0) {
          u32* sp = bar + gid * 32 + (lane & 31);
          while (__ballot((int)(__hip_atomic_load(sp, __ATOMIC_RELAXED,
                                                  __HIP_MEMORY_SCOPE_AGENT) <
                                (u32)t)))
            __builtin_amdgcn_s_sleep(1);
        }
        __syncthreads();

        const u16* hp =
            hbuf + ((t - 1) & 1) * (2L * NB * NH) + ((long)d * NB + m0) * NH;
        // stage h chunk (64 rows x 128 k = 16 KB) via LDS-DMA, SC1 (LLC)
        auto stage = [&](int it, int pb) {
          char* dst = hstg + pb * 16384;
#pragma unroll
          for (int p = 0; p < 4; ++p) {
            int c = p * 256 + tid;  // [0,1024)
            int row = c >> 4, slot = c & 15;
            int half = slot >> 3, ck = slot & 7;
            int kk = it * 128 + half * 64 + ((ck * 8) ^ ((row & 7) << 3));
            const u16* gsrc = hp + (long)row * NH + kk;
            __builtin_amdgcn_global_load_lds(
                (const __attribute__((address_space(1))) void*)(const void*)gsrc,
                (__attribute__((address_space(3))) void*)(dst + p * 4096 +
                                                          wv * 1024),
                16, 0, 16 /* SC1: agent-coherent read from LLC */);
          }
        };
        stage(0, 0);
        __syncthreads();
#pragma unroll 1
        for (int it = 0; it < 4; ++it) {
          if (it + 1 < 4) stage(it + 1, (it + 1) & 1);
          const u16* As = (const u16*)(hstg + (it & 1) * 16384);
#pragma unroll
          for (int ks = 0; ks < 4; ++ks) {
            const int ksub = ks * 32 + quad * 8;  // [0,128)
            int rm = wv * 16 + col;
            int sla = (ksub & 63) ^ ((rm & 7) << 3);
            short8 afr = *(const short8*)(As + rm * 128 + (ksub & 64) + sla);
            const int kc = it * 128 + ksub;
#pragma unroll
            for (int g = 0; g < 4; ++g) {
              int br = d * 64 + g * 16 + col;
              int slb = (kc & 63) ^ ((br & 7) << 3);
              short8 bfr = *(const short8*)(Bs + br * 512 + (kc & ~63) + slb);
              acc[g] = __builtin_amdgcn_mfma_f32_16x16x32_bf16(afr, bfr,
                                                               acc[g], 0, 0, 0);
            }
          }
          if (it + 1 < 4) __syncthreads();
        }
      }

      // ---- register-only cell update; pack h into 2 KB LDS ----
#pragma unroll
      for (int r = 0; r < 4; ++r) {
        int m = wv * 16 + quad * 4 + r;
        float gi = acc[0][r] + bf2f(xgv[r].x);
        float gf = acc[1][r] + bf2f(xgv[r].y);
        float gg = acc[2][r] + bf2f(xgv[r].z);
        float go = acc[3][r] + bf2f(xgv[r].w);
        float si = sigm(gi);
        float sf = sigm(gf);
        float so = sigm(go);
        float cn = sf * creg[d][r] + si * fast_tanh(gg);
        float h = so * fast_tanh(cn);
        creg[d][r] = cn;
        hLDS[m * 16 + col] = f2bf(h);
        // fp32 output path: store full-precision h directly (rare rows)
        if (layer == 1 && !isbf) {
          int bg = m0 + m;
          if (qlen[bg] - 1 == tq)
            ((float*)outp)[(long)bg * (2 * NH) + d * NH + j0 + col] = h;
        }
      }
      __syncthreads();

      // ---- hbuf (LLC) stores first; keep values in regs for HBM stores ----
      u16* hnxt = hbuf + (t & 1) * (2L * NB * NH);
      u32 hw[2];
      int bgp[2], jgp[2];
#pragma unroll
      for (int p = 0; p < 2; ++p) {
        int c = p * 256 + tid;  // [0,512) pairs
        int m = c >> 3, pr = c & 7;
        hw[p] = ((const u32*)hLDS)[m * 8 + pr];
        bgp[p] = m0 + m;
        jgp[p] = j0 + pr * 2;
        __hip_atomic_store(
            (u32*)(hnxt + ((long)d * NB + bgp[p]) * NH + jgp[p]), hw[p],
            __ATOMIC_RELAXED, __HIP_MEMORY_SCOPE_AGENT);
      }

      // ---- drain hbuf stores, then signal (per-writer slot) ----
      if (t < NW - 1) {
        __syncthreads();  // vmcnt(0): hbuf stores visible at LLC
        if (tid == 0)
          __hip_atomic_store(bar + gid * 32 + colb, (u32)(t + 1),
                             __ATOMIC_RELAXED, __HIP_MEMORY_SCOPE_AGENT);
      }

      // ---- deferred HBM stores (off the signal's critical path) ----
#pragma unroll
      for (int p = 0; p < 2; ++p) {
        if (layer == 0) {
          *(u32*)(h0cat + ((long)tq * NB + bgp[p]) * (2 * NH) + d * NH +
                  jgp[p]) = hw[p];
        } else if (isbf && qlen[bgp[p]] - 1 == tq) {
          *(u32*)((u16*)outp + (long)bgp[p] * (2 * NH) + d * NH + jgp[p]) =
              hw[p];
        }
      }
    }
  }
}

extern "C" void kernel_launch(void* const* d_in, const int* in_sizes, int n_in,
                              void* d_out, int out_size, void* d_ws,
                              size_t ws_size, hipStream_t stream) {
  const int* qv = (const int*)d_in[0];
  const int* ql = (const int*)d_in[1];
  const void* lookup = d_in[2];
  const void* wih0 = d_in[3];
  const void* whh0 = d_in[4];
  const void* b0 = d_in[5];
  const void* wih1 = d_in[6];
  const void* whh1 = d_in[7];
  const void* b1 = d_in[8];

  char* ws = (char*)d_ws;
  size_t off = 0;
  int* flag = (int*)ws;                 off += 256;
  unsigned int* bar = (unsigned int*)(ws + off); off += 8192;
  float* bsum = (float*)(ws + off);     off += 2L * 2 * G4 * 4;        // 32 KB
  u16* Wc0 = (u16*)(ws + off);          off += 2L * G4 * 1024 * 2;     // 8 MB
  u16* Wc1 = (u16*)(ws + off);          off += 2L * G4 * 1536 * 2;     // 12 MB
  u16* hbuf = (u16*)(ws + off);         off += 2L * 2 * NB * NH * 2;   // 2 MB
  u16* h0cat = (u16*)(ws + off);        off += (size_t)NW * NB * 2 * NH * 2; // 40 MB
  u16* emb = (u16*)(ws + off);          off += (size_t)NW * NB * NE * 2;     // 20 MB
  u16* xg = (u16*)(ws + off);           off += (size_t)NW * 2 * 16 * 512 * 128 * 2; // 168 MB
  u16* tableT = h0cat;  // tableT (12.3 MB) aliases h0cat: dead before layer0

  detect_kernel<<<1, 64, 0, stream>>>((const u16*)lookup, flag);
  table_kernel<<<dim3(188, 8), dim3(64, 4), 0, stream>>>(lookup, flag, tableT);
  {
    long total = 2L * G4 * 1024 + 2L * G4 * 1536 + 2L * 2 * G4;
    int blocks = (int)((total + 255) / 256);
    pack_kernel<<<blocks, 256, 0, stream>>>(wih0, whh0, b0, wih1, whh1, b1,
                                            flag, Wc0, Wc1, bsum);
  }
  embed_kernel<<<NW * NB / 4, 256, 0, stream>>>(qv, tableT, emb);

  // layer 0
  xg_gemm<<<5120, 256, 0, stream>>>(emb, 512, 1024, Wc0, bsum, xg);
  zero_bar<<<8, 256, 0, stream>>>(bar);
  lstm_pers<<<256, 256, 0, stream>>>(xg, Wc0, 1024, 512, hbuf, h0cat, d_out,
                                     ql, flag, bar, 0);
  // layer 1
  xg_gemm<<<5120, 256, 0, stream>>>(h0cat, 1024, 1536, Wc1, bsum + 2 * G4, xg);
  zero_bar<<<8, 256, 0, stream>>>(bar);
  lstm_pers<<<256, 256, 0, stream>>>(xg, Wc1, 1536, 1024, hbuf, h0cat, d_out,
                                     ql, flag, bar, 1);
}

// Round 3
// 1002.424 us; speedup vs baseline: 1.2622x; 1.0535x over previous
//
#include <hip/hip_runtime.h>
#include <hip/hip_bf16.h>
#include <stdint.h>

#define NB 512
#define NW 40
#define NE 512
#define NH 512
#define NV 12000
#define G4 2048

typedef unsigned short u16;
typedef unsigned int u32;
typedef unsigned long long u64;
typedef __attribute__((ext_vector_type(8))) short short8;
typedef __attribute__((ext_vector_type(4))) float f32x4;

__device__ __forceinline__ unsigned short f2bf(float f) {
  unsigned int u = __float_as_uint(f);
  u += 0x7FFF + ((u >> 16) & 1);
  return (unsigned short)(u >> 16);
}
__device__ __forceinline__ float bf2f(unsigned short b) {
  return __uint_as_float(((unsigned int)b) << 16);
}
__device__ __forceinline__ float loadIn(const void* p, long i, int bf) {
  return bf ? bf2f(((const u16*)p)[i]) : ((const float*)p)[i];
}
// exp-based tanh: |err| ~1e-7 abs, saturates cleanly (exp->inf => 1).
__device__ __forceinline__ float fast_tanh(float x) {
  float ax = __builtin_fabsf(x);
  float t = 1.f - 2.f * __builtin_amdgcn_rcpf(__expf(ax + ax) + 1.f);
  return __builtin_copysignf(t, x);
}
__device__ __forceinline__ float sigm(float x) {
  return __builtin_amdgcn_rcpf(1.f + __expf(-x));
}

// ---------------- dtype detector ----------------
__global__ void detect_kernel(const u16* p, int* flag) {
  __shared__ int cnt;
  int i = threadIdx.x;
  if (i == 0) cnt = 0;
  __syncthreads();
  unsigned short u = p[2 * (i * 1001)];
  int e = (u >> 7) & 0xFF;
  if (e >= 100 && e <= 126) atomicAdd(&cnt, 1);
  __syncthreads();
  if (i == 0) *flag = (cnt >= 32) ? 1 : 0;
}

// ---------------- tableT = bf16(tanh(lookup_W^T)), (V, E) ----------------
__global__ void table_kernel(const void* lookup, const int* flag, u16* tableT) {
  __shared__ float tile[64][65];
  int bf = *flag;
  int v0 = blockIdx.x * 64, e0 = blockIdx.y * 64;
  int tx = threadIdx.x, ty = threadIdx.y;  // (64,4)
#pragma unroll
  for (int r = 0; r < 16; ++r) {
    int e = r * 4 + ty, v = tx;
    if (v0 + v < NV)
      tile[e][v] = tanhf(loadIn(lookup, (long)(e0 + e) * NV + v0 + v, bf));
  }
  __syncthreads();
#pragma unroll
  for (int r = 0; r < 16; ++r) {
    int v = r * 4 + ty, e = tx;
    if (v0 + v < NV)
      tableT[(long)(v0 + v) * NE + e0 + e] = f2bf(tile[e][v]);
  }
}

// ---------------- emb (W*B, E) bf16, rows tb = t*NB+b ----------------
__global__ void embed_kernel(const int* __restrict__ qv,
                             const u16* __restrict__ tableT,
                             u16* __restrict__ emb) {
  int tid = blockIdx.x * 256 + threadIdx.x;
  int token = tid >> 6;
  int chunk = tid & 63;
  int tt = token / NB, b = token % NB;
  int q = qv[b * NW + tt];
  uint4 val = make_uint4(0u, 0u, 0u, 0u);
  if (q > 0) val = *(const uint4*)(tableT + (long)(q - 1) * NE + chunk * 8);
  *(uint4*)(emb + (long)token * NE + chunk * 8) = val;
}

// ---------------- pack weights: Wc[d] rows = [wih | whh], bf16 ------------
__global__ void pack_kernel(const void* wih0, const void* whh0, const void* b0,
                            const void* wih1, const void* whh1, const void* b1,
                            const int* flag, u16* Wc0, u16* Wc1, float* bsum) {
  const long N0 = 2L * G4 * 1024, N1 = 2L * G4 * 1536;
  long idx = (long)blockIdx.x * 256 + threadIdx.x;
  int bf = *flag;
  if (idx < N0) {
    int d = (int)(idx / (G4 * 1024));
    int rem = (int)(idx % (long)(G4 * 1024));
    int g = rem / 1024, k = rem % 1024;
    float v = (k < 512) ? loadIn(wih0, ((long)d * G4 + g) * 512 + k, bf)
                        : loadIn(whh0, ((long)d * G4 + g) * 512 + (k - 512), bf);
    Wc0[idx] = f2bf(v);
  } else if (idx < N0 + N1) {
    long i2 = idx - N0;
    int d = (int)(i2 / (G4 * 1536));
    int rem = (int)(i2 % (long)(G4 * 1536));
    int g = rem / 1536, k = rem % 1536;
    float v = (k < 1024) ? loadIn(wih1, ((long)d * G4 + g) * 1024 + k, bf)
                         : loadIn(whh1, ((long)d * G4 + g) * 512 + (k - 1024), bf);
    Wc1[i2] = f2bf(v);
  } else if (idx < N0 + N1 + 2L * 2 * G4) {
    long i3 = idx - N0 - N1;  // [layer][d][g]
    int layer = (int)(i3 / (2 * G4));
    int d = (int)((i3 / G4) & 1);
    int g = (int)(i3 % G4);
    const void* bb = layer ? b1 : b0;
    float v = loadIn(bb, (long)d * 2 * G4 + g, bf) +
              loadIn(bb, (long)d * 2 * G4 + G4 + g, bf);
    bsum[i3] = v;
  }
}

// ---------------- zero the barrier (8 KB) ----------------
__global__ void zero_bar(unsigned int* bar) {
  bar[blockIdx.x * 256 + threadIdx.x] = 0u;
}

// ---------------- xg GEMM: xg[t][d][col][b][jn*4+g] = X@Wih^T + bias ------
// 128x128 tile, BK=64, m97-style staging, 4 waves 2x2.
// 1D grid + supertile swizzle (4 bx x 8 by contiguous) so A-tiles
// (4x256KB) and B-tiles (8x256KB) stay cache-resident across reuse.
__global__ __launch_bounds__(256, 2) void xg_gemm(
    const u16* __restrict__ X, int Kx, int Kfull, const u16* __restrict__ Wc,
    const float* __restrict__ bsumL, u16* __restrict__ xg) {
  __shared__ __align__(16) char lds[32768];  // A 16K + B 16K
  const int tid = threadIdx.x;
  const int lane = tid & 63, wv = tid >> 6;
  const int wm = wv & 1, wn = wv >> 1;
  const int col = lane & 15, quad = lane >> 4;
  const int s = blockIdx.x >> 5, w = blockIdx.x & 31;
  const int bx = (s % 40) * 4 + (w & 3);
  const int by = (s / 40) * 8 + (w >> 2);
  const int tb0 = bx * 128;
  const int d = by >> 4, colb = by & 15, j0 = colb * 32;

  f32x4 zero = {0.f, 0.f, 0.f, 0.f};
  f32x4 acc[4][4];
#pragma unroll
  for (int i = 0; i < 4; ++i)
#pragma unroll
    for (int j = 0; j < 4; ++j) acc[i][j] = zero;

  const int iters = Kx >> 6;
  for (int it = 0; it < iters; ++it) {
    int k0 = it << 6;
#pragma unroll
    for (int p = 0; p < 8; ++p) {
      int c = p * 256 + tid;  // [0,2048)
      const u16* gsrc;
      if (c < 1024) {  // A rows 0..127
        int r = c >> 3, sl = c & 7;
        int kk = k0 + ((sl * 8) ^ ((r & 7) << 3));
        gsrc = X + (long)(tb0 + r) * Kx + kk;
      } else {
        int cb = c - 1024;
        int r = cb >> 3, sl = cb & 7;
        int kk = k0 + ((sl * 8) ^ ((r & 7) << 3));
        int grow = (r >> 5) * 512 + j0 + (r & 31);
        gsrc = Wc + ((long)d * G4 + grow) * Kfull + kk;
      }
      __builtin_amdgcn_global_load_lds(
          (const __attribute__((address_space(1))) void*)(const void*)gsrc,
          (__attribute__((address_space(3))) void*)(lds + p * 4096 + wv * 1024),
          16, 0, 0);
    }
    __syncthreads();
    const u16* As = (const u16*)lds;
    const u16* Bs = (const u16*)(lds + 16384);
#pragma unroll
    for (int ks = 0; ks < 2; ++ks) {
      short8 afr[4], bfr[4];
#pragma unroll
      for (int mf = 0; mf < 4; ++mf) {
        int rm = wm * 64 + mf * 16 + col;
        int sl = (ks * 32 + quad * 8) ^ ((rm & 7) << 3);
        afr[mf] = *(const short8*)(As + rm * 64 + sl);
      }
#pragma unroll
      for (int nf = 0; nf < 4; ++nf) {
        int br = wn * 64 + nf * 16 + col;
        int sl = (ks * 32 + quad * 8) ^ ((br & 7) << 3);
        bfr[nf] = *(const short8*)(Bs + br * 64 + sl);
      }
#pragma unroll
      for (int mf = 0; mf < 4; ++mf)
#pragma unroll
        for (int nf = 0; nf < 4; ++nf)
          acc[mf][nf] = __builtin_amdgcn_mfma_f32_16x16x32_bf16(
              afr[mf], bfr[nf], acc[mf][nf], 0, 0, 0);
    }
    __syncthreads();
  }

  float bias[4];
#pragma unroll
  for (int nf = 0; nf < 4; ++nf) {
    int n = wn * 64 + nf * 16 + col;
    bias[nf] = bsumL[d * G4 + (n >> 5) * 512 + j0 + (n & 31)];
  }
#pragma unroll
  for (int mf = 0; mf < 4; ++mf)
#pragma unroll
    for (int nf = 0; nf < 4; ++nf) {
      int n = wn * 64 + nf * 16 + col;
      int g = n >> 5, jn = n & 31;
#pragma unroll
      for (int r = 0; r < 4; ++r) {
        int m = wm * 64 + mf * 16 + quad * 4 + r;
        int tb = tb0 + m, t = tb >> 9, b = tb & 511;
        long oi = ((((long)t * 2 + d) * 16 + colb) * 512 + b) * 128 + jn * 4 + g;
        xg[oi] = f2bf(acc[mf][nf][r] + bias[nf]);
      }
    }
}

// ---------------- persistent bidirectional LSTM recurrence ----------------
// R11: wave-independent agents -- ZERO __syncthreads() in the 40-step loop.
// R10 post-mortem: doubling phase count (d-interleave) added fixed latency;
// the real cost is the per-step serial chain x lockstep. Here each wave owns
// rows wv*16..+16 of the block's 64-row slice and computes ALL 32 cols x 4
// gates for them (A-frag rows of 16x16x32 are col-indexed -> wave-private):
//  * h-stage: wave-private 2x4KB LDS dbuf, global_load_lds (SC1) with
//    COUNTED vmcnt(4) waits (T4) -- no barriers, 2-deep pipeline.
//  * flags: per-wave slots bar[(gid*4+wv)*16+colb]; reader wave polls its
//    16 writer waves (same wv class) with a 16-lane ballot. Waves of
//    different wv never interact; the 2-slot hbuf safety argument holds
//    wave-granularly (X waits Y's flag(t) before writing h(t+1) => Y done
//    reading h(t-1)).
//  * cell, pack, stores all wave-local; per-wave vmcnt(0) then flag.
//  * 4 waves/CU drift freely -> each other's stalls overlap.
// Cost accepted: each wave reads all 128 Whh B-rows (2x B LDS traffic).
// Stores stay 64B-contiguous per row (full-line h0cat writes, R10 lesson).
// sched_barrier(0) fences pin the manual vmcnt accounting (guide rule 18).
__global__ __launch_bounds__(256, 1) void lstm_pers(
    const u16* __restrict__ xg, const u16* __restrict__ Wc, int Kfull, int Kx,
    u16* __restrict__ hbuf, u16* __restrict__ h0cat, void* __restrict__ outp,
    const int* __restrict__ qlen, const int* __restrict__ flag,
    unsigned int* bar, int layer) {
  __shared__ __align__(16) char lds[163840];  // [Whh 128K][4 waves x 2x4K]
  const int tid = threadIdx.x;
  const int lane = tid & 63, wv = tid >> 6;
  const int col = lane & 15, quad = lane >> 4;
  const int l = blockIdx.x;
  const int colid = l & 31, mi = l >> 5;
  const int colb = colid & 15, d = colid >> 4;
  const int j0 = colb * 32;
  const int m0 = mi * 64;
  const int gid = l >> 4;   // mi*2 + d
  const int r0 = wv * 16;   // wave's batch-row offset within m0

  // ---- preload Whh slice [128 rows = [g 4][jn 32]][512 k], swizzled ----
#pragma unroll
  for (int p = 0; p < 32; ++p) {
    int c = p * 256 + tid;
    int row = c >> 6, rem = c & 63;
    int kc = rem >> 3, sl = rem & 7;
    int grow = (row >> 5) * 512 + j0 + (row & 31);
    int gk = Kx + kc * 64 + ((sl * 8) ^ ((row & 7) << 3));
    const u16* gsrc = Wc + ((long)d * G4 + grow) * Kfull + gk;
    __builtin_amdgcn_global_load_lds(
        (const __attribute__((address_space(1))) void*)(const void*)gsrc,
        (__attribute__((address_space(3))) void*)(lds + p * 4096 + wv * 1024),
        16, 0, 0);
  }
  const u16* Bs = (const u16*)lds;
  char* wbuf = lds + 131072 + wv * 8192;  // wave-private 2 x 4 KB stage
  u16* packb = (u16*)wbuf;  // 1 KB h-pack, aliases buf0 (dead after it=2)

  float creg[2][4];
#pragma unroll
  for (int i = 0; i < 2; ++i)
#pragma unroll
    for (int r = 0; r < 4; ++r) creg[i][r] = 0.f;
  const int isbf = *flag;
  f32x4 zero = {0.f, 0.f, 0.f, 0.f};

  __syncthreads();  // Whh resident (the ONLY block barrier in this kernel)

#pragma unroll 1
  for (int t = 0; t < NW; ++t) {
    const int tq = d ? (NW - 1 - t) : t;

    // xg prefetch (independent of the wait): b = m0+r0+quad*4+r
    ushort4 xgv[2][4];
    const u16* xgt =
        xg + ((((long)tq * 2 + d) * 16 + colb) * 512 + m0 + r0) * 128;
#pragma unroll
    for (int js = 0; js < 2; ++js)
#pragma unroll
      for (int r = 0; r < 4; ++r)
        xgv[js][r] =
            *(const ushort4*)(xgt + (quad * 4 + r) * 128 + (js * 16 + col) * 4);
    __builtin_amdgcn_sched_barrier(0);

    f32x4 acc[8];
#pragma unroll
    for (int g = 0; g < 8; ++g) acc[g] = zero;

    if (t > 0) {
      // ---- per-wave poll: the 16 writer waves (gid, wv, colb' 0..15) ----
      {
        u32* sp = bar + ((gid * 4 + wv) << 4) + col;  // lanes>=16 duplicate
        while (__ballot((int)(__hip_atomic_load(sp, __ATOMIC_RELAXED,
                                                __HIP_MEMORY_SCOPE_AGENT) <
                              (u32)t)))
          __builtin_amdgcn_s_sleep(1);
      }
      __builtin_amdgcn_sched_barrier(0);

      const u16* hp = hbuf + ((t - 1) & 1) * (2L * NB * NH) +
                      ((long)d * NB + m0 + r0) * NH;
      // wave-private stage: 16 rows x 128 k = 4 KB per chunk, SC1 (LLC)
      auto stage = [&](int it) {
        char* dst = wbuf + (it & 1) * 4096;
#pragma unroll
        for (int i = 0; i < 4; ++i) {
          int c = i * 64 + lane;
          int row = c >> 4, slot = c & 15;
          int half = slot >> 3, ck = slot & 7;
          int kk = it * 128 + half * 64 + ((ck * 8) ^ ((row & 7) << 3));
          const u16* gsrc = hp + (long)row * NH + kk;
          __builtin_amdgcn_global_load_lds(
              (const __attribute__((address_space(1))) void*)(const void*)gsrc,
              (__attribute__((address_space(3))) void*)(dst + i * 1024), 16, 0,
              16 /* SC1: agent-coherent read from LLC */);
        }
      };
      stage(0);
      stage(1);
#pragma unroll
      for (int it = 0; it < 4; ++it) {
        // chunk `it` ready: after this wait, <=4 outstanding (next chunk(s))
        if (it < 3)
          asm volatile("s_waitcnt vmcnt(4)" ::: "memory");
        else
          asm volatile("s_waitcnt vmcnt(0)" ::: "memory");
        const u16* As = (const u16*)(wbuf + (it & 1) * 4096);
        short8 afr[4];
#pragma unroll
        for (int ks = 0; ks < 4; ++ks) {
          int ksub = ks * 32 + quad * 8;
          afr[ks] = *(const short8*)(As + col * 128 + (ksub & 64) +
                                     ((ksub & 63) ^ ((col & 7) << 3)));
        }
        if (it < 2) {
          // buf (it&1) reads retired before re-staging into it
          asm volatile("s_waitcnt lgkmcnt(0)" ::: "memory");
          __builtin_amdgcn_sched_barrier(0);
          stage(it + 2);
        }
#pragma unroll
        for (int ks = 0; ks < 4; ++ks) {
          const int kc = it * 128 + ks * 32 + quad * 8;
#pragma unroll
          for (int nf = 0; nf < 8; ++nf) {
            int br = nf * 16 + col;
            int slb = (kc & 63) ^ ((br & 7) << 3);
            short8 bfr = *(const short8*)(Bs + br * 512 + (kc & ~63) + slb);
            acc[nf] = __builtin_amdgcn_mfma_f32_16x16x32_bf16(afr[ks], bfr,
                                                              acc[nf], 0, 0, 0);
          }
        }
      }
    }

    // ---- wave-local cell update; pack h into wave's 1 KB LDS ----
#pragma unroll
    for (int js = 0; js < 2; ++js)
#pragma unroll
      for (int r = 0; r < 4; ++r) {
        const u16* xv = (const u16*)&xgv[js][r];
        float gi = acc[0 * 2 + js][r] + bf2f(xv[0]);
        float gf = acc[1 * 2 + js][r] + bf2f(xv[1]);
        float gg = acc[2 * 2 + js][r] + bf2f(xv[2]);
        float go = acc[3 * 2 + js][r] + bf2f(xv[3]);
        float si = sigm(gi);
        float sf = sigm(gf);
        float so = sigm(go);
        float cn = sf * creg[js][r] + si * fast_tanh(gg);
        float h = so * fast_tanh(cn);
        creg[js][r] = cn;
        packb[(quad * 4 + r) * 32 + js * 16 + col] = f2bf(h);
        // fp32 output path: store full-precision h directly (rare rows)
        if (layer == 1 && !isbf) {
          int bg = m0 + r0 + quad * 4 + r;
          if (qlen[bg] - 1 == tq)
            ((float*)outp)[(long)bg * (2 * NH) + d * NH + j0 + js * 16 + col] =
                h;
        }
      }

    // ---- wave-local coalesced stores from the pack (64 B per row) ----
    const int srow = lane >> 2, part = lane & 3;
    u64 v0, v1;
    {
      const u64* pp = (const u64*)(packb + srow * 32 + part * 8);
      v0 = pp[0];
      v1 = pp[1];
    }
    u16* hnxt = hbuf + (t & 1) * (2L * NB * NH);
    {
      u64* hdst = (u64*)(hnxt + ((long)d * NB + m0 + r0 + srow) * NH + j0 +
                         part * 8);
      __hip_atomic_store(hdst, v0, __ATOMIC_RELAXED, __HIP_MEMORY_SCOPE_AGENT);
      __hip_atomic_store(hdst + 1, v1, __ATOMIC_RELAXED,
                         __HIP_MEMORY_SCOPE_AGENT);
    }

    // ---- per-wave drain, then signal own flag slot ----
    if (t < NW - 1) {
      asm volatile("s_waitcnt vmcnt(0)" ::: "memory");
      if (lane == 0)
        __hip_atomic_store(bar + ((gid * 4 + wv) << 4) + colb, (u32)(t + 1),
                           __ATOMIC_RELAXED, __HIP_MEMORY_SCOPE_AGENT);
    }

    // ---- deferred HBM stores (off the signal's critical path) ----
    if (layer == 0) {
      u16* dst = h0cat + ((long)tq * NB + m0 + r0 + srow) * (2 * NH) + d * NH +
                 j0 + part * 8;
      *(u64*)dst = v0;
      *((u64*)dst + 1) = v1;
    } else if (isbf) {
      int bg = m0 + r0 + srow;
      if (qlen[bg] - 1 == tq) {
        u16* dst = (u16*)outp + (long)bg * (2 * NH) + d * NH + j0 + part * 8;
        *(u64*)dst = v0;
        *((u64*)dst + 1) = v1;
      }
    }
    __builtin_amdgcn_sched_barrier(0);
  }
}

extern "C" void kernel_launch(void* const* d_in, const int* in_sizes, int n_in,
                              void* d_out, int out_size, void* d_ws,
                              size_t ws_size, hipStream_t stream) {
  const int* qv = (const int*)d_in[0];
  const int* ql = (const int*)d_in[1];
  const void* lookup = d_in[2];
  const void* wih0 = d_in[3];
  const void* whh0 = d_in[4];
  const void* b0 = d_in[5];
  const void* wih1 = d_in[6];
  const void* whh1 = d_in[7];
  const void* b1 = d_in[8];

  char* ws = (char*)d_ws;
  size_t off = 0;
  int* flag = (int*)ws;                 off += 256;
  unsigned int* bar = (unsigned int*)(ws + off); off += 8192;
  float* bsum = (float*)(ws + off);     off += 2L * 2 * G4 * 4;        // 32 KB
  u16* Wc0 = (u16*)(ws + off);          off += 2L * G4 * 1024 * 2;     // 8 MB
  u16* Wc1 = (u16*)(ws + off);          off += 2L * G4 * 1536 * 2;     // 12 MB
  u16* hbuf = (u16*)(ws + off);         off += 2L * 2 * NB * NH * 2;   // 2 MB
  u16* h0cat = (u16*)(ws + off);        off += (size_t)NW * NB * 2 * NH * 2; // 40 MB
  u16* emb = (u16*)(ws + off);          off += (size_t)NW * NB * NE * 2;     // 20 MB
  u16* xg = (u16*)(ws + off);           off += (size_t)NW * 2 * 16 * 512 * 128 * 2; // 168 MB
  u16* tableT = h0cat;  // tableT (12.3 MB) aliases h0cat: dead before layer0

  detect_kernel<<<1, 64, 0, stream>>>((const u16*)lookup, flag);
  table_kernel<<<dim3(188, 8), dim3(64, 4), 0, stream>>>(lookup, flag, tableT);
  {
    long total = 2L * G4 * 1024 + 2L * G4 * 1536 + 2L * 2 * G4;
    int blocks = (int)((total + 255) / 256);
    pack_kernel<<<blocks, 256, 0, stream>>>(wih0, whh0, b0, wih1, whh1, b1,
                                            flag, Wc0, Wc1, bsum);
  }
  embed_kernel<<<NW * NB / 4, 256, 0, stream>>>(qv, tableT, emb);

  // layer 0
  xg_gemm<<<5120, 256, 0, stream>>>(emb, 512, 1024, Wc0, bsum, xg);
  zero_bar<<<8, 256, 0, stream>>>(bar);
  lstm_pers<<<256, 256, 0, stream>>>(xg, Wc0, 1024, 512, hbuf, h0cat, d_out,
                                     ql, flag, bar, 0);
  // layer 1
  xg_gemm<<<5120, 256, 0, stream>>>(h0cat, 1024, 1536, Wc1, bsum + 2 * G4, xg);
  zero_bar<<<8, 256, 0, stream>>>(bar);
  lstm_pers<<<256, 256, 0, stream>>>(xg, Wc1, 1536, 1024, hbuf, h0cat, d_out,
                                     ql, flag, bar, 1);
}